// Round 27
// baseline (1479.966 us; speedup 1.0000x reference)
//
#include <hip/hip_runtime.h>
#include <hip/hip_bf16.h>
#include <stdint.h>

typedef __attribute__((ext_vector_type(4))) float f32x4;
typedef __attribute__((ext_vector_type(16))) float f32x16;
typedef __attribute__((ext_vector_type(4))) int i32x4;
typedef __attribute__((ext_vector_type(8))) int i32x8;
typedef __attribute__((ext_vector_type(8))) short bh8;
typedef unsigned short u16;
typedef unsigned int u32;
typedef unsigned char u8;

#define B_    8
#define C_    512
#define LF    16384
#define KTOT  1536
#define SCL   0x7F7F7F7Fu   // e8m0 1.0 in all bytes

// ws layout (bytes): P4 bf16
#define P4_BYTES ((size_t)4 * B_ * 21 * LF * 2)      // 22,020,096
#define W8_OFF   P4_BYTES

// output chunk offsets (float32 elements)
#define OBJ_OFF  0
#define REG_OFF  917504
#define ANC_OFF  2752512

__device__ __forceinline__ u32 pk2bf(float lo, float hi) {
    u32 r;
    asm("v_cvt_pk_bf16_f32 %0, %1, %2" : "=v"(r) : "v"(lo), "v"(hi));
    return r;
}
__device__ __forceinline__ u16 f2bf(float f) {
    u32 u = __float_as_uint(f);
    return (u16)((u + 0x7FFFu + ((u >> 16) & 1u)) >> 16);
}
__device__ __forceinline__ float bf2f(u16 h) {
    return __uint_as_float(((u32)h) << 16);
}
__device__ __forceinline__ void gload16(const u8* g, u8* l) {
    __builtin_amdgcn_global_load_lds(
        (const __attribute__((address_space(1))) void*)g,
        (__attribute__((address_space(3))) void*)l, 16, 0, 0);
}

// ---- cast conv_w -> W8 fp8 e4m3, t-major K, 16B-slot swizzle baked in ----
__global__ void k_cast_w(const float* __restrict__ cw, u8* __restrict__ W8) {
    int i = blockIdx.x * 256 + threadIdx.x;          // byte-pair index
    if (i >= C_ * KTOT / 2) return;
    int co = i / (KTOT / 2);
    int rr = (i % (KTOT / 2)) * 2;                   // phys byte in row (even)
    int t = rr / 512, q = rr % 512;
    int kc = q >> 6, cc = q & 63;
    int jl = (cc >> 4) ^ ((co >> 1) & 3);
    int ci = kc * 64 + jl * 16 + (cc & 15);
    float f0 = cw[(co * C_ + ci) * 3 + t];
    float f1 = cw[(co * C_ + ci + 1) * 3 + t];
    u32 pk = __builtin_amdgcn_cvt_pk_fp8_f32(f0, f1, 0, false);
    *(u16*)&W8[(size_t)co * KTOT + rr] = (u16)pk;
}

// ---- MX-fp8 conv GEMM (32x32x64), B-regs pipelined across kc; 4 blk/CU ----
// grid: 4096 blocks, XCD-swizzled mt-quads; 256 threads (4 waves, 2x2)
__global__ __launch_bounds__(256, 4) void k_conv_head(
    const float* __restrict__ feat, const u8* __restrict__ W8,
    const float* __restrict__ conv_b, const float* __restrict__ obj_w,
    const float* __restrict__ reg_w, u16* __restrict__ P4) {
    __shared__ __align__(16) char smem[33024];
    u8* As3 = (u8*)smem;                 // [3][128][64] fp8, linear gload dest
    u8* Bs  = (u8*)(smem + 24576);       // [130][64] fp8, slot-swizzled
    u16* Hs = (u16*)smem;                // [64][128] bf16 epilogue (overlay)
    u16* Wp = (u16*)(smem + 16384);      // [32][128] bf16 epilogue (overlay)

    const int tid = threadIdx.x;
    const int lane = tid & 63, wave = tid >> 6;
    const int wm = wave >> 1, wn = wave & 1;
    const int g = lane >> 4, cL = lane & 15;
    const int r32 = lane & 31, hK = lane >> 5;       // 32x32 frag coords

    const int wg = (blockIdx.x & 7) * 512 + (blockIdx.x >> 3);
    const int mt = wg & 3;
    const int l0 = ((wg >> 2) & 127) * 128;
    const int b  = wg >> 9;
    const int co0 = mt * 128;

    const int cg = tid & 15, lgrp = tid >> 4;
    const int slog = cg >> 2, soff = (cg * 4) & 15;
    const int haloci = tid >> 1;
    const int halorr = (tid & 1) ? 129 : 0;
    const int halodl = (tid & 1) ? 128 : -1;
    const int halopc = (((haloci >> 4) ^ ((halorr >> 1) & 3)) * 16) + (haloci & 15);

    f32x16 acc[2][2];
#pragma unroll
    for (int mi = 0; mi < 2; ++mi)
#pragma unroll
        for (int ni = 0; ni < 2; ++ni)
#pragma unroll
            for (int r = 0; r < 16; ++r) acc[mi][ni][r] = 0.f;

    // ---- prologue: load B(0) into regs ----
    float4 fvC[8];
    float hvC = 0.f;
    {
        const float* fp = feat + ((size_t)(b * C_ + cg * 4)) * LF + l0 + lgrp * 8;
#pragma unroll
        for (int h = 0; h < 2; ++h)
#pragma unroll
            for (int j = 0; j < 4; ++j)
                fvC[h * 4 + j] = *(const float4*)(fp + (size_t)j * LF + h * 4);
        if (tid < 128) {
            const int l = l0 + halodl;
            hvC = (l >= 0 && l < LF)
                      ? feat[((size_t)(b * C_ + haloci)) * LF + l] : 0.f;
        }
    }

#pragma unroll
    for (int kc = 0; kc < 8; ++kc) {
        __syncthreads();                 // barrier#1: MFMA(kc-1) LDS reads done
        // ---- issue A for ALL 3 taps (DMA, lands under cvt+write phase) ----
#pragma unroll
        for (int t = 0; t < 3; ++t)
#pragma unroll
            for (int p = 0; p < 2; ++p) {
                const int row = p * 64 + (tid >> 2);
                const int colB = (tid & 3) * 16;
                gload16(&W8[(size_t)(co0 + row) * KTOT + t * 512 + kc * 64 + colB],
                        &As3[t * 8192 + row * 64 + colB]);
            }
        // ---- write B(kc) from regs (loaded during MFMA(kc-1); no load wait) ----
#pragma unroll
        for (int h = 0; h < 2; ++h)
#pragma unroll
            for (int e = 0; e < 4; ++e) {
                const int r = 1 + lgrp * 8 + h * 4 + e;
                u32 w0 = __builtin_amdgcn_cvt_pk_fp8_f32(
                    ((const float*)&fvC[h * 4 + 0])[e],
                    ((const float*)&fvC[h * 4 + 1])[e], 0, false);
                u32 w  = __builtin_amdgcn_cvt_pk_fp8_f32(
                    ((const float*)&fvC[h * 4 + 2])[e],
                    ((const float*)&fvC[h * 4 + 3])[e], w0, true);
                const int pc = ((slog ^ ((r >> 1) & 3)) * 16) + soff;
                *(u32*)&Bs[r * 64 + pc] = w;
            }
        if (tid < 128) {
            u32 p = __builtin_amdgcn_cvt_pk_fp8_f32(hvC, 0.f, 0, false);
            Bs[halorr * 64 + halopc] = (u8)p;
        }
        __syncthreads();                 // barrier#2: A-DMA + ds_writes drained
        // ---- load B(kc+1) regs (issued alongside MFMA; lands by next bar#1) ----
        if (kc < 7) {
            const float* fp = feat +
                ((size_t)(b * C_ + (kc + 1) * 64 + cg * 4)) * LF + l0 + lgrp * 8;
#pragma unroll
            for (int h = 0; h < 2; ++h)
#pragma unroll
                for (int j = 0; j < 4; ++j)
                    fvC[h * 4 + j] = *(const float4*)(fp + (size_t)j * LF + h * 4);
            if (tid < 128) {
                const int l = l0 + halodl;
                hvC = (l >= 0 && l < LF)
                          ? feat[((size_t)(b * C_ + (kc + 1) * 64 + haloci)) * LF + l]
                          : 0.f;
            }
        }
        // ---- compute: 3 taps x 4 scaled-MFMA (32x32x64) ----
#pragma unroll
        for (int t = 0; t < 3; ++t) {
            const u8* At = As3 + t * 8192;
            i32x8 af[2], bf[2];
#pragma unroll
            for (int mi = 0; mi < 2; ++mi) {
                const int row = wm * 64 + mi * 32 + r32;
                const int x = (row >> 1) & 3;
                i32x4 a0 = *(const i32x4*)&At[row * 64 + (((2 * hK) ^ x) * 16)];
                i32x4 a1 = *(const i32x4*)&At[row * 64 + (((2 * hK + 1) ^ x) * 16)];
                af[mi] = __builtin_shufflevector(a0, a1, 0, 1, 2, 3, 4, 5, 6, 7);
            }
#pragma unroll
            for (int ni = 0; ni < 2; ++ni) {
                const int row = wn * 64 + ni * 32 + r32 + t;
                const int x = (row >> 1) & 3;
                i32x4 b0 = *(const i32x4*)&Bs[row * 64 + (((2 * hK) ^ x) * 16)];
                i32x4 b1 = *(const i32x4*)&Bs[row * 64 + (((2 * hK + 1) ^ x) * 16)];
                bf[ni] = __builtin_shufflevector(b0, b1, 0, 1, 2, 3, 4, 5, 6, 7);
            }
#pragma unroll
            for (int mi = 0; mi < 2; ++mi)
#pragma unroll
                for (int ni = 0; ni < 2; ++ni)
                    acc[mi][ni] = __builtin_amdgcn_mfma_scale_f32_32x32x64_f8f6f4(
                        af[mi], bf[ni], acc[mi][ni], 0, 0, 0, SCL, 0, SCL);
        }
    }
    __syncthreads();                     // K-loop LDS reads done; overlay Hs/Wp

    // ---- stage Wp[a][c] (a<7 obj, 7..20 reg, 21..31 zero), swizzled ----
#pragma unroll
    for (int it = 0; it < 4; ++it) {
        const int q = it * 256 + tid;
        const int a = q >> 5, c0 = (q & 31) * 4;
        float4 wv = {0.f, 0.f, 0.f, 0.f};
        if (a < 7)       wv = *(const float4*)&obj_w[a * C_ + co0 + c0];
        else if (a < 21) wv = *(const float4*)&reg_w[(a - 7) * C_ + co0 + c0];
        uint2 pk;
        pk.x = pk2bf(wv.x, wv.y);
        pk.y = pk2bf(wv.z, wv.w);
        *(uint2*)&Wp[a * 128 + (c0 ^ ((a & 7) << 3))] = pk;
    }

    u16* P4base = P4 + ((size_t)(mt * B_ + b) * 21) * LF + l0;
    // ---- two 64-l halves: epilogue Hs -> head MFMA -> P4 (bf16) ----
#pragma unroll
    for (int half = 0; half < 2; ++half) {
        if (wn == half) {
#pragma unroll
            for (int mi = 0; mi < 2; ++mi)
#pragma unroll
                for (int ni = 0; ni < 2; ++ni) {
                    const int l_half = ni * 32 + r32;        // 0..63
                    const int xw = (l_half & 7) << 3;
#pragma unroll
                    for (int q = 0; q < 4; ++q) {
                        const int cb = wm * 64 + mi * 32 + q * 8 + 4 * hK;
                        const float b0_ = conv_b[co0 + cb + 0];
                        const float b1_ = conv_b[co0 + cb + 1];
                        const float b2_ = conv_b[co0 + cb + 2];
                        const float b3_ = conv_b[co0 + cb + 3];
                        uint2 pk;
                        pk.x = pk2bf(fmaxf(acc[mi][ni][q * 4 + 0] + b0_, 0.f),
                                     fmaxf(acc[mi][ni][q * 4 + 1] + b1_, 0.f));
                        pk.y = pk2bf(fmaxf(acc[mi][ni][q * 4 + 2] + b2_, 0.f),
                                     fmaxf(acc[mi][ni][q * 4 + 3] + b3_, 0.f));
                        *(uint2*)&Hs[l_half * 128 + (cb ^ xw)] = pk;
                    }
                }
        }
        __syncthreads();                 // Hs (+Wp first pass) visible

        f32x4 hacc0 = {0.f, 0.f, 0.f, 0.f};
        f32x4 hacc1 = {0.f, 0.f, 0.f, 0.f};
        const int lrow = wave * 16 + cL;
        const int swA = (cL & 7) << 3;
#pragma unroll
        for (int ks2 = 0; ks2 < 4; ++ks2) {
            const int ko = ks2 * 32 + g * 8;
            bh8 wa0 = *(const bh8*)&Wp[cL * 128 + (ko ^ swA)];
            bh8 wa1 = *(const bh8*)&Wp[(16 + cL) * 128 + (ko ^ swA)];
            bh8 hb  = *(const bh8*)&Hs[lrow * 128 + (ko ^ swA)];
            hacc0 = __builtin_amdgcn_mfma_f32_16x16x32_bf16(wa0, hb, hacc0, 0, 0, 0);
            hacc1 = __builtin_amdgcn_mfma_f32_16x16x32_bf16(wa1, hb, hacc1, 0, 0, 0);
        }
        const int lg = half * 64 + lrow;
#pragma unroll
        for (int m = 0; m < 2; ++m) {
            const int a0 = m * 16 + g * 4;
            const f32x4 hv = (m == 0) ? hacc0 : hacc1;
#pragma unroll
            for (int r = 0; r < 4; ++r) {
                const int a = a0 + r;
                if (a < 21) P4base[(size_t)a * LF + lg] = f2bf(hv[r]);
            }
        }
        __syncthreads();                 // head reads done before next-half writes
    }
}

// ---- reduce partials (bf16), add biases, write f32 obj/reg + anchors ----
__global__ void k_finalize(const u16* __restrict__ P4, const float* __restrict__ obj_b,
                           const float* __restrict__ reg_b, float* __restrict__ out) {
    int gid = blockIdx.x * 256 + threadIdx.x;
    if (gid >= B_ * LF) return;
    int b = gid >> 14, l = gid & (LF - 1);
    float s[21];
#pragma unroll
    for (int a = 0; a < 21; ++a) {
        float v = 0.f;
#pragma unroll
        for (int m = 0; m < 4; ++m)
            v += bf2f(P4[((size_t)(m * B_ + b) * 21 + a) * LF + l]);
        s[a] = v;
    }
    float* op = out + OBJ_OFF + (size_t)b * (LF * 7) + (size_t)l * 7;
#pragma unroll
    for (int a = 0; a < 7; ++a) op[a] = s[a] + obj_b[a];
    float* rp = out + REG_OFF + (size_t)b * (LF * 14) + (size_t)l * 14;
#pragma unroll
    for (int o = 0; o < 14; ++o) rp[o] = s[7 + o] + reg_b[o];
    if (b == 0) {
        const float AL[7] = {1.f, 2.f, 3.f, 4.f, 5.f, 7.f, 9.f};
        float* an = out + ANC_OFF + (size_t)l * 14;
        float c = (float)l + 0.5f;
#pragma unroll
        for (int a = 0; a < 7; ++a) {
            an[a * 2 + 0] = c - 0.5f * AL[a];
            an[a * 2 + 1] = c + 0.5f * AL[a];
        }
    }
}

extern "C" void kernel_launch(void* const* d_in, const int* in_sizes, int n_in,
                              void* d_out, int out_size, void* d_ws, size_t ws_size,
                              hipStream_t stream) {
    const float* feat   = (const float*)d_in[0];
    const float* conv_w = (const float*)d_in[1];
    const float* conv_b = (const float*)d_in[2];
    const float* obj_w  = (const float*)d_in[3];
    const float* obj_b  = (const float*)d_in[4];
    const float* reg_w  = (const float*)d_in[5];
    const float* reg_b  = (const float*)d_in[6];
    char* ws = (char*)d_ws;
    u16* P4 = (u16*)ws;
    u8* W8  = (u8*)(ws + W8_OFF);
    float* out = (float*)d_out;

    k_cast_w<<<1536, 256, 0, stream>>>(conv_w, W8);
    k_conv_head<<<4096, 256, 0, stream>>>(feat, W8, conv_b, obj_w, reg_w, P4);
    k_finalize<<<(B_ * LF + 255) / 256, 256, 0, stream>>>(P4, obj_b, reg_b, out);
}

// Round 28
// 221.169 us; speedup vs baseline: 6.6916x; 6.6916x over previous
//
#include <hip/hip_runtime.h>
#include <hip/hip_bf16.h>
#include <stdint.h>

typedef __attribute__((ext_vector_type(4))) float f32x4;
typedef __attribute__((ext_vector_type(16))) float f32x16;
typedef __attribute__((ext_vector_type(4))) int i32x4;
typedef __attribute__((ext_vector_type(8))) int i32x8;
typedef __attribute__((ext_vector_type(8))) short bh8;
typedef unsigned short u16;
typedef unsigned int u32;
typedef unsigned char u8;

#define B_    8
#define C_    512
#define LF    16384
#define KTOT  1536
#define SCL   0x7F7F7F7Fu   // e8m0 1.0 in all bytes

// ws layout (bytes): P4 bf16
#define P4_BYTES ((size_t)4 * B_ * 21 * LF * 2)      // 22,020,096
#define W8_OFF   P4_BYTES

// output chunk offsets (float32 elements)
#define OBJ_OFF  0
#define REG_OFF  917504
#define ANC_OFF  2752512

__device__ __forceinline__ u32 pk2bf(float lo, float hi) {
    u32 r;
    asm("v_cvt_pk_bf16_f32 %0, %1, %2" : "=v"(r) : "v"(lo), "v"(hi));
    return r;
}
__device__ __forceinline__ u16 f2bf(float f) {
    u32 u = __float_as_uint(f);
    return (u16)((u + 0x7FFFu + ((u >> 16) & 1u)) >> 16);
}
__device__ __forceinline__ float bf2f(u16 h) {
    return __uint_as_float(((u32)h) << 16);
}
__device__ __forceinline__ void gload16(const u8* g, u8* l) {
    __builtin_amdgcn_global_load_lds(
        (const __attribute__((address_space(1))) void*)g,
        (__attribute__((address_space(3))) void*)l, 16, 0, 0);
}

// ---- cast conv_w -> W8 fp8 e4m3, t-major K, 16B-slot swizzle baked in ----
// physical slot jp of row co holds logical slot jp ^ ((co>>1)&3)
__global__ void k_cast_w(const float* __restrict__ cw, u8* __restrict__ W8) {
    int i = blockIdx.x * 256 + threadIdx.x;          // byte-pair index
    if (i >= C_ * KTOT / 2) return;
    int co = i / (KTOT / 2);
    int rr = (i % (KTOT / 2)) * 2;                   // phys byte in row (even)
    int t = rr / 512, q = rr % 512;
    int kc = q >> 6, cc = q & 63;
    int jl = (cc >> 4) ^ ((co >> 1) & 3);
    int ci = kc * 64 + jl * 16 + (cc & 15);
    float f0 = cw[(co * C_ + ci) * 3 + t];
    float f1 = cw[(co * C_ + ci + 1) * 3 + t];
    u32 pk = __builtin_amdgcn_cvt_pk_fp8_f32(f0, f1, 0, false);
    *(u16*)&W8[(size_t)co * KTOT + rr] = (u16)pk;
}

// ---- MX-fp8 conv GEMM (32x32x64) + fused bf16 head -> P4 (bf16); 4 blk/CU ----
// grid: 4096 blocks, XCD-swizzled mt-quads; 256 threads (4 waves, 2x2)
__global__ __launch_bounds__(256, 4) void k_conv_head(
    const float* __restrict__ feat, const u8* __restrict__ W8,
    const float* __restrict__ conv_b, const float* __restrict__ obj_w,
    const float* __restrict__ reg_w, u16* __restrict__ P4) {
    __shared__ __align__(16) char smem[33024];
    u8* As3 = (u8*)smem;                 // [3][128][64] fp8, linear gload dest
    u8* Bs  = (u8*)(smem + 24576);       // [130][64] fp8, slot-swizzled
    u16* Hs = (u16*)smem;                // [64][128] bf16 epilogue (overlay)
    u16* Wp = (u16*)(smem + 16384);      // [32][128] bf16 epilogue (overlay)

    const int tid = threadIdx.x;
    const int lane = tid & 63, wave = tid >> 6;
    const int wm = wave >> 1, wn = wave & 1;
    const int g = lane >> 4, cL = lane & 15;
    const int r32 = lane & 31, hK = lane >> 5;       // 32x32 frag coords

    const int wg = (blockIdx.x & 7) * 512 + (blockIdx.x >> 3);
    const int mt = wg & 3;
    const int l0 = ((wg >> 2) & 127) * 128;
    const int b  = wg >> 9;
    const int co0 = mt * 128;

    const int cg = tid & 15, lgrp = tid >> 4;

    f32x16 acc[2][2];
#pragma unroll
    for (int mi = 0; mi < 2; ++mi)
#pragma unroll
        for (int ni = 0; ni < 2; ++ni)
#pragma unroll
            for (int r = 0; r < 16; ++r) acc[mi][ni][r] = 0.f;

    for (int kc = 0; kc < 8; ++kc) {
        __syncthreads();                 // prior readers of As3/Bs done
        // ---- issue A for ALL 3 taps FIRST (latency hidden under B-stage) ----
#pragma unroll
        for (int t = 0; t < 3; ++t)
#pragma unroll
            for (int p = 0; p < 2; ++p) {
                const int row = p * 64 + (tid >> 2);
                const int colB = (tid & 3) * 16;
                gload16(&W8[(size_t)(co0 + row) * KTOT + t * 512 + kc * 64 + colB],
                        &As3[t * 8192 + row * 64 + colB]);
            }
        // ---- stage Bs rows 1..128 (fp8, pk-cvt + u32 swizzled writes) ----
        {
            const float* fp = feat +
                ((size_t)(b * C_ + kc * 64 + cg * 4)) * LF + l0 + lgrp * 8;
            const int slog = cg >> 2;                // logical 16B slot
            const int soff = (cg * 4) & 15;
#pragma unroll
            for (int h = 0; h < 2; ++h) {
                float4 v0 = *(const float4*)(fp + 0 * LF + h * 4);
                float4 v1 = *(const float4*)(fp + 1 * LF + h * 4);
                float4 v2 = *(const float4*)(fp + 2 * LF + h * 4);
                float4 v3 = *(const float4*)(fp + 3 * LF + h * 4);
#pragma unroll
                for (int e = 0; e < 4; ++e) {
                    const int r = 1 + lgrp * 8 + h * 4 + e;
                    u32 w0 = __builtin_amdgcn_cvt_pk_fp8_f32(
                        ((const float*)&v0)[e], ((const float*)&v1)[e], 0, false);
                    u32 w  = __builtin_amdgcn_cvt_pk_fp8_f32(
                        ((const float*)&v2)[e], ((const float*)&v3)[e], w0, true);
                    const int pc = ((slog ^ ((r >> 1) & 3)) * 16) + soff;
                    *(u32*)&Bs[r * 64 + pc] = w;
                }
            }
        }
        // ---- halo rows r=0 (l0-1), r=129 (l0+128) ----
        if (tid < 128) {
            const int ci2 = tid >> 1;
            const int rr = (tid & 1) ? 129 : 0;
            const int l = l0 + ((tid & 1) ? 128 : -1);
            float v = (l >= 0 && l < LF)
                          ? feat[((size_t)(b * C_ + kc * 64 + ci2)) * LF + l]
                          : 0.f;
            u32 p = __builtin_amdgcn_cvt_pk_fp8_f32(v, 0.f, 0, false);
            const int pc = (((ci2 >> 4) ^ ((rr >> 1) & 3)) * 16) + (ci2 & 15);
            Bs[rr * 64 + pc] = (u8)p;
        }
        __syncthreads();                 // drains gloads + ds_writes; all ready
        // ---- compute: 3 taps x 4 scaled-MFMA (32x32x64) ----
#pragma unroll
        for (int t = 0; t < 3; ++t) {
            const u8* At = As3 + t * 8192;
            i32x8 af[2], bf[2];
#pragma unroll
            for (int mi = 0; mi < 2; ++mi) {
                const int row = wm * 64 + mi * 32 + r32;
                const int x = (row >> 1) & 3;
                i32x4 a0 = *(const i32x4*)&At[row * 64 + (((2 * hK) ^ x) * 16)];
                i32x4 a1 = *(const i32x4*)&At[row * 64 + (((2 * hK + 1) ^ x) * 16)];
                af[mi] = __builtin_shufflevector(a0, a1, 0, 1, 2, 3, 4, 5, 6, 7);
            }
#pragma unroll
            for (int ni = 0; ni < 2; ++ni) {
                const int row = wn * 64 + ni * 32 + r32 + t;
                const int x = (row >> 1) & 3;
                i32x4 b0 = *(const i32x4*)&Bs[row * 64 + (((2 * hK) ^ x) * 16)];
                i32x4 b1 = *(const i32x4*)&Bs[row * 64 + (((2 * hK + 1) ^ x) * 16)];
                bf[ni] = __builtin_shufflevector(b0, b1, 0, 1, 2, 3, 4, 5, 6, 7);
            }
#pragma unroll
            for (int mi = 0; mi < 2; ++mi)
#pragma unroll
                for (int ni = 0; ni < 2; ++ni)
                    acc[mi][ni] = __builtin_amdgcn_mfma_scale_f32_32x32x64_f8f6f4(
                        af[mi], bf[ni], acc[mi][ni], 0, 0, 0, SCL, 0, SCL);
        }
    }
    __syncthreads();                     // K-loop LDS reads done; overlay Hs/Wp

    // ---- stage Wp[a][c] (a<7 obj, 7..20 reg, 21..31 zero), swizzled ----
#pragma unroll
    for (int it = 0; it < 4; ++it) {
        const int q = it * 256 + tid;
        const int a = q >> 5, c0 = (q & 31) * 4;
        float4 wv = {0.f, 0.f, 0.f, 0.f};
        if (a < 7)       wv = *(const float4*)&obj_w[a * C_ + co0 + c0];
        else if (a < 21) wv = *(const float4*)&reg_w[(a - 7) * C_ + co0 + c0];
        uint2 pk;
        pk.x = pk2bf(wv.x, wv.y);
        pk.y = pk2bf(wv.z, wv.w);
        *(uint2*)&Wp[a * 128 + (c0 ^ ((a & 7) << 3))] = pk;
    }

    u16* P4base = P4 + ((size_t)(mt * B_ + b) * 21) * LF + l0;
    // ---- two 64-l halves: epilogue Hs -> head MFMA -> P4 (bf16) ----
#pragma unroll
    for (int half = 0; half < 2; ++half) {
        if (wn == half) {
#pragma unroll
            for (int mi = 0; mi < 2; ++mi)
#pragma unroll
                for (int ni = 0; ni < 2; ++ni) {
                    const int l_half = ni * 32 + r32;        // 0..63
                    const int xw = (l_half & 7) << 3;
#pragma unroll
                    for (int q = 0; q < 4; ++q) {
                        const int cb = wm * 64 + mi * 32 + q * 8 + 4 * hK;
                        const float b0_ = conv_b[co0 + cb + 0];
                        const float b1_ = conv_b[co0 + cb + 1];
                        const float b2_ = conv_b[co0 + cb + 2];
                        const float b3_ = conv_b[co0 + cb + 3];
                        uint2 pk;
                        pk.x = pk2bf(fmaxf(acc[mi][ni][q * 4 + 0] + b0_, 0.f),
                                     fmaxf(acc[mi][ni][q * 4 + 1] + b1_, 0.f));
                        pk.y = pk2bf(fmaxf(acc[mi][ni][q * 4 + 2] + b2_, 0.f),
                                     fmaxf(acc[mi][ni][q * 4 + 3] + b3_, 0.f));
                        *(uint2*)&Hs[l_half * 128 + (cb ^ xw)] = pk;
                    }
                }
        }
        __syncthreads();                 // Hs (+Wp first pass) visible

        f32x4 hacc0 = {0.f, 0.f, 0.f, 0.f};
        f32x4 hacc1 = {0.f, 0.f, 0.f, 0.f};
        const int lrow = wave * 16 + cL;
        const int swA = (cL & 7) << 3;
#pragma unroll
        for (int ks2 = 0; ks2 < 4; ++ks2) {
            const int ko = ks2 * 32 + g * 8;
            bh8 wa0 = *(const bh8*)&Wp[cL * 128 + (ko ^ swA)];
            bh8 wa1 = *(const bh8*)&Wp[(16 + cL) * 128 + (ko ^ swA)];
            bh8 hb  = *(const bh8*)&Hs[lrow * 128 + (ko ^ swA)];
            hacc0 = __builtin_amdgcn_mfma_f32_16x16x32_bf16(wa0, hb, hacc0, 0, 0, 0);
            hacc1 = __builtin_amdgcn_mfma_f32_16x16x32_bf16(wa1, hb, hacc1, 0, 0, 0);
        }
        const int lg = half * 64 + lrow;
#pragma unroll
        for (int m = 0; m < 2; ++m) {
            const int a0 = m * 16 + g * 4;
            const f32x4 hv = (m == 0) ? hacc0 : hacc1;
#pragma unroll
            for (int r = 0; r < 4; ++r) {
                const int a = a0 + r;
                if (a < 21) P4base[(size_t)a * LF + lg] = f2bf(hv[r]);
            }
        }
        __syncthreads();                 // head reads done before next-half writes
    }
}

// ---- reduce partials (bf16), add biases, write f32 obj/reg + anchors ----
__global__ void k_finalize(const u16* __restrict__ P4, const float* __restrict__ obj_b,
                           const float* __restrict__ reg_b, float* __restrict__ out) {
    int gid = blockIdx.x * 256 + threadIdx.x;
    if (gid >= B_ * LF) return;
    int b = gid >> 14, l = gid & (LF - 1);
    float s[21];
#pragma unroll
    for (int a = 0; a < 21; ++a) {
        float v = 0.f;
#pragma unroll
        for (int m = 0; m < 4; ++m)
            v += bf2f(P4[((size_t)(m * B_ + b) * 21 + a) * LF + l]);
        s[a] = v;
    }
    float* op = out + OBJ_OFF + (size_t)b * (LF * 7) + (size_t)l * 7;
#pragma unroll
    for (int a = 0; a < 7; ++a) op[a] = s[a] + obj_b[a];
    float* rp = out + REG_OFF + (size_t)b * (LF * 14) + (size_t)l * 14;
#pragma unroll
    for (int o = 0; o < 14; ++o) rp[o] = s[7 + o] + reg_b[o];
    if (b == 0) {
        const float AL[7] = {1.f, 2.f, 3.f, 4.f, 5.f, 7.f, 9.f};
        float* an = out + ANC_OFF + (size_t)l * 14;
        float c = (float)l + 0.5f;
#pragma unroll
        for (int a = 0; a < 7; ++a) {
            an[a * 2 + 0] = c - 0.5f * AL[a];
            an[a * 2 + 1] = c + 0.5f * AL[a];
        }
    }
}

extern "C" void kernel_launch(void* const* d_in, const int* in_sizes, int n_in,
                              void* d_out, int out_size, void* d_ws, size_t ws_size,
                              hipStream_t stream) {
    const float* feat   = (const float*)d_in[0];
    const float* conv_w = (const float*)d_in[1];
    const float* conv_b = (const float*)d_in[2];
    const float* obj_w  = (const float*)d_in[3];
    const float* obj_b  = (const float*)d_in[4];
    const float* reg_w  = (const float*)d_in[5];
    const float* reg_b  = (const float*)d_in[6];
    char* ws = (char*)d_ws;
    u16* P4 = (u16*)ws;
    u8* W8  = (u8*)(ws + W8_OFF);
    float* out = (float*)d_out;

    k_cast_w<<<1536, 256, 0, stream>>>(conv_w, W8);
    k_conv_head<<<4096, 256, 0, stream>>>(feat, W8, conv_b, obj_w, reg_w, P4);
    k_finalize<<<(B_ * LF + 255) / 256, 256, 0, stream>>>(P4, obj_b, reg_b, out);
}